// Round 1
// baseline (1326.930 us; speedup 1.0000x reference)
//
#include <hip/hip_runtime.h>

typedef unsigned short u16;
typedef unsigned int   u32;
typedef unsigned long long u64;
typedef __attribute__((ext_vector_type(8))) short s16x8;
typedef __attribute__((ext_vector_type(4))) float f32x4;

// Problem dims
constexpr int B = 8192, D = 1024, H = 4096, O = 1024, E = 16, CAP = 1024;
constexpr int EG = 4;            // experts per group (workspace cap)
constexpr int NGROUP = E / EG;

__device__ __forceinline__ u16 f2bf(float f) {
  u32 u = __float_as_uint(f);
  u32 r = (u + 0x7FFFu + ((u >> 16) & 1u)) >> 16;   // RNE
  return (u16)r;
}

// ---------------------------------------------------------------- zero d_out
__global__ __launch_bounds__(256) void zero_kernel(float4* __restrict__ p, int n4) {
  int i = blockIdx.x * blockDim.x + threadIdx.x;
  int stride = gridDim.x * blockDim.x;
  float4 z; z.x = z.y = z.z = z.w = 0.0f;
  for (; i < n4; i += stride) p[i] = z;
}

// ---------------------------------------------------------------- router logits
__global__ __launch_bounds__(256) void router_kernel(const float* __restrict__ x,
    const float* __restrict__ Wr, const float* __restrict__ br,
    float* __restrict__ logits) {
  int t = blockIdx.x * 256 + threadIdx.x;     // [0, B*E)
  int b = t >> 4, e = t & 15;
  const float* xr = x + (size_t)b * D;
  float acc = 0.f;
#pragma unroll 8
  for (int k = 0; k < D; k++) acc = fmaf(xr[k], Wr[k * E + e], acc);
  logits[t] = acc + br[e];
}

// ---------------------------------------------------------------- softmax over token axis (per expert column)
__global__ __launch_bounds__(1024) void softmax_colwise(const float* __restrict__ logits,
                                                        float* __restrict__ probs) {
  __shared__ float red[16];
  int e = blockIdx.x, t = threadIdx.x;
  float l[8];
  float mx = -1e30f;
#pragma unroll
  for (int i = 0; i < 8; i++) {
    l[i] = logits[(size_t)(t + i * 1024) * E + e];
    mx = fmaxf(mx, l[i]);
  }
#pragma unroll
  for (int o = 32; o > 0; o >>= 1) mx = fmaxf(mx, __shfl_xor(mx, o));
  if ((t & 63) == 0) red[t >> 6] = mx;
  __syncthreads();
  if (t < 64) {
    float v = (t < 16) ? red[t] : -1e30f;
#pragma unroll
    for (int o = 8; o > 0; o >>= 1) v = fmaxf(v, __shfl_xor(v, o));
    if (t == 0) red[0] = v;
  }
  __syncthreads();
  mx = red[0];
  __syncthreads();
  float s = 0.f;
#pragma unroll
  for (int i = 0; i < 8; i++) { l[i] = expf(l[i] - mx); s += l[i]; }
#pragma unroll
  for (int o = 32; o > 0; o >>= 1) s += __shfl_xor(s, o);
  if ((t & 63) == 0) red[t >> 6] = s;
  __syncthreads();
  if (t < 64) {
    float v = (t < 16) ? red[t] : 0.f;
#pragma unroll
    for (int o = 8; o > 0; o >>= 1) v += __shfl_xor(v, o);
    if (t == 0) red[0] = v;
  }
  __syncthreads();
  float inv = 1.0f / red[0];
#pragma unroll
  for (int i = 0; i < 8; i++)
    probs[(size_t)(t + i * 1024) * E + e] = l[i] * inv;
}

// ---------------------------------------------------------------- per-expert top-1024 via bitonic sort (desc, tie -> lower idx)
__global__ __launch_bounds__(1024) void topk_bitonic(const float* __restrict__ probs,
    float* __restrict__ scores, int* __restrict__ tidx, float* __restrict__ mask) {
  __shared__ u64 d[8192];                      // 64 KB
  int e = blockIdx.x, t = threadIdx.x;
  for (int i = t; i < B; i += 1024) {
    float p = probs[(size_t)i * E + e];
    d[i] = ((u64)__float_as_uint(p) << 32) | (u32)(0xFFFFFFFFu - (u32)i);
  }
  __syncthreads();
  for (int k = 2; k <= B; k <<= 1) {
    for (int j = k >> 1; j > 0; j >>= 1) {
      for (int i = t; i < B; i += 1024) {
        int l = i ^ j;
        if (l > i) {
          u64 a = d[i], b2 = d[l];
          bool descBlk = (i & k) == 0;
          if (descBlk ? (a < b2) : (a > b2)) { d[i] = b2; d[l] = a; }
        }
      }
      __syncthreads();
    }
  }
  u64 v = d[t];                                // t in [0,1024) = top-1024
  float p = __uint_as_float((u32)(v >> 32));
  int b = (int)(0xFFFFFFFFu - (u32)v);
  scores[e * CAP + t] = p;
  tidx[e * CAP + t] = b;
  mask[(size_t)b * E + e] = 1.0f;
}

// ---------------------------------------------------------------- gather selected token rows -> bf16
__global__ __launch_bounds__(256) void gather_bf16(const float* __restrict__ x,
    const int* __restrict__ tidx, u16* __restrict__ Abf) {
  int blk = blockIdx.x;                        // e*CAP + c
  int row = tidx[blk];
  const float4* src = (const float4*)(x + (size_t)row * D);
  int t = threadIdx.x;
  float4 v = src[t];
  uint2 u;
  u.x = f2bf(v.x) | ((u32)f2bf(v.y) << 16);
  u.y = f2bf(v.z) | ((u32)f2bf(v.w) << 16);
  ((uint2*)(Abf + (size_t)blk * D))[t] = u;
}

// ---------------------------------------------------------------- transpose + f32->bf16: in [EG][DR][DC] -> out [EG][DC][DR]
template <int DR, int DC>
__global__ __launch_bounds__(256) void transpose_convert(const float* __restrict__ in,
                                                         u16* __restrict__ out) {
  __shared__ float tile[64][68];
  constexpr int TR = DR / 64, TC = DC / 64;
  int bid = blockIdx.x;
  int e = bid / (TR * TC);
  int rem = bid % (TR * TC);
  int tr = rem / TC, tc = rem % TC;
  int t = threadIdx.x;
  int r0 = t >> 4;            // 0..15
  int c0 = (t & 15) << 2;     // 0..60
  const float* src = in + (size_t)e * DR * DC + (size_t)(tr * 64) * DC + (size_t)tc * 64;
#pragma unroll
  for (int p = 0; p < 4; p++) {
    float4 v = *(const float4*)(src + (size_t)(p * 16 + r0) * DC + c0);
    tile[p * 16 + r0][c0 + 0] = v.x;
    tile[p * 16 + r0][c0 + 1] = v.y;
    tile[p * 16 + r0][c0 + 2] = v.z;
    tile[p * 16 + r0][c0 + 3] = v.w;
  }
  __syncthreads();
  u16* dst = out + (size_t)e * DR * DC + (size_t)(tc * 64) * DR + (size_t)tr * 64;
#pragma unroll
  for (int p = 0; p < 4; p++) {
    int hl = p * 16 + r0;
    uint2 u;
    u.x = f2bf(tile[c0 + 0][hl]) | ((u32)f2bf(tile[c0 + 1][hl]) << 16);
    u.y = f2bf(tile[c0 + 2][hl]) | ((u32)f2bf(tile[c0 + 3][hl]) << 16);
    *(uint2*)(dst + (size_t)hl * DR + c0) = u;
  }
}

// ---------------------------------------------------------------- batched bf16 GEMM, m97-style 128x128 tile, BK=64
// A: [EG][1024][KTOT] bf16 row-major. Bt: [EG][NTOT][KTOT] bf16 (B transposed).
// EPI 0: Hout = relu(A@B + bias) as bf16 [EG][1024][NTOT]
// EPI 1: atomicAdd(out[tok], (A@B + bias) * score)
template <int EPI, int NTOT, int KTOT>
__global__ __launch_bounds__(256, 2) void moe_gemm(const u16* __restrict__ A,
    const u16* __restrict__ Bt, const float* __restrict__ bias,
    u16* __restrict__ Hout, float* __restrict__ outp,
    const float* __restrict__ scores, const int* __restrict__ tidx) {
  constexpr int NTM = 1024 / 128, NTN = NTOT / 128, NKT = KTOT / 64;
  __shared__ u16 Alds[128 * 64];
  __shared__ u16 Blds[128 * 64];
  int bid = blockIdx.x;
  int e = bid / (NTM * NTN);
  int rem = bid % (NTM * NTN);
  int tm = rem / NTN, tn = rem % NTN;
  int tid = threadIdx.x, w = tid >> 6, lane = tid & 63;
  int wr = w >> 1, wc = w & 1;

  const u16* Abase = A + ((size_t)e * 1024 + tm * 128) * KTOT;
  const u16* Bbase = Bt + ((size_t)e * NTOT + tn * 128) * KTOT;
  int srow = lane >> 3;            // 0..7
  int scol = (lane & 7) * 8;       // bf16 elements (16B)

  f32x4 acc[4][4];
#pragma unroll
  for (int m = 0; m < 4; m++)
#pragma unroll
    for (int n = 0; n < 4; n++) { f32x4 z = {0.f, 0.f, 0.f, 0.f}; acc[m][n] = z; }

  for (int kt = 0; kt < NKT; kt++) {
    const u16* Ak = Abase + kt * 64;
    const u16* Bk = Bbase + kt * 64;
#pragma unroll
    for (int i = 0; i < 4; i++) {
      int grp = w * 4 + i;                 // 0..15
      int row = grp * 8 + srow;            // 0..127
      __builtin_amdgcn_global_load_lds(
          (const __attribute__((address_space(1))) void*)(Ak + (size_t)row * KTOT + scol),
          (__attribute__((address_space(3))) void*)(&Alds[grp * 512]), 16, 0, 0);
      __builtin_amdgcn_global_load_lds(
          (const __attribute__((address_space(1))) void*)(Bk + (size_t)row * KTOT + scol),
          (__attribute__((address_space(3))) void*)(&Blds[grp * 512]), 16, 0, 0);
    }
    __syncthreads();
#pragma unroll
    for (int kk = 0; kk < 2; kk++) {
      int kb = kk * 32 + (lane >> 4) * 8;
      s16x8 a[4], bfr[4];
#pragma unroll
      for (int m = 0; m < 4; m++)
        a[m] = *(const s16x8*)&Alds[(wr * 64 + m * 16 + (lane & 15)) * 64 + kb];
#pragma unroll
      for (int n = 0; n < 4; n++)
        bfr[n] = *(const s16x8*)&Blds[(wc * 64 + n * 16 + (lane & 15)) * 64 + kb];
#pragma unroll
      for (int m = 0; m < 4; m++)
#pragma unroll
        for (int n = 0; n < 4; n++)
          acc[m][n] = __builtin_amdgcn_mfma_f32_16x16x32_bf16(a[m], bfr[n], acc[m][n], 0, 0, 0);
    }
    __syncthreads();
  }

  int colb = tn * 128 + wc * 64 + (lane & 15);
  float bv[4];
#pragma unroll
  for (int n = 0; n < 4; n++) bv[n] = bias[(size_t)e * NTOT + colb + n * 16];

  if constexpr (EPI == 0) {
    u16* Hb = Hout + (size_t)e * 1024 * NTOT;
#pragma unroll
    for (int m = 0; m < 4; m++) {
#pragma unroll
      for (int j = 0; j < 4; j++) {
        int r = tm * 128 + wr * 64 + m * 16 + (lane >> 4) * 4 + j;
#pragma unroll
        for (int n = 0; n < 4; n++) {
          float v = acc[m][n][j] + bv[n];
          v = fmaxf(v, 0.0f);
          Hb[(size_t)r * NTOT + colb + n * 16] = f2bf(v);
        }
      }
    }
  } else {
#pragma unroll
    for (int m = 0; m < 4; m++) {
#pragma unroll
      for (int j = 0; j < 4; j++) {
        int rc = tm * 128 + wr * 64 + m * 16 + (lane >> 4) * 4 + j;
        float sc = scores[e * CAP + rc];
        int tok = tidx[e * CAP + rc];
        float* orow = outp + (size_t)tok * O;
#pragma unroll
        for (int n = 0; n < 4; n++) {
          float v = (acc[m][n][j] + bv[n]) * sc;
          atomicAdd(&orow[colb + n * 16], v);
        }
      }
    }
  }
}

// ----------------------------------------------------------------
extern "C" void kernel_launch(void* const* d_in, const int* in_sizes, int n_in,
                              void* d_out, int out_size, void* d_ws, size_t ws_size,
                              hipStream_t stream) {
  const float* x  = (const float*)d_in[0];
  const float* Wr = (const float*)d_in[1];
  const float* br = (const float*)d_in[2];
  const float* W1 = (const float*)d_in[3];
  const float* b1 = (const float*)d_in[4];
  const float* W2 = (const float*)d_in[5];
  const float* b2 = (const float*)d_in[6];

  float* out   = (float*)d_out;                 // [B][O]
  float* probs = out + (size_t)B * O;           // [B][E]
  float* mask  = probs + (size_t)B * E;         // [B][E]

  // workspace layout (~97 MB)
  char* ws = (char*)d_ws;
  float* logits  = (float*)ws;                              // 512 KB
  float* scoresW = (float*)(ws + (512u << 10));             // 64 KB
  int*   idxW    = (int*)(ws + (576u << 10));               // 64 KB
  u16* Abf = (u16*)(ws + (1u << 20));                       // 32 MB  [E][CAP][D]
  u16* Wt  = (u16*)(ws + (1u << 20) + (32u << 20));         // 32 MB  per-group [EG][N][K]
  u16* Hbf = (u16*)(ws + (1u << 20) + (64u << 20));         // 32 MB  per-group [EG][CAP][H]
  if (ws_size < ((1u << 20) + (96u << 20))) return;         // insufficient scratch -> visible failure

  zero_kernel<<<2048, 256, 0, stream>>>((float4*)d_out, (B * O + 2 * B * E) / 4);
  router_kernel<<<(B * E) / 256, 256, 0, stream>>>(x, Wr, br, logits);
  softmax_colwise<<<E, 1024, 0, stream>>>(logits, probs);
  topk_bitonic<<<E, 1024, 0, stream>>>(probs, scoresW, idxW, mask);
  gather_bf16<<<E * CAP, 256, 0, stream>>>(x, idxW, Abf);

  for (int g = 0; g < NGROUP; g++) {
    const float* W1g = W1 + (size_t)g * EG * D * H;
    const float* W2g = W2 + (size_t)g * EG * H * O;
    // W1 [EG][D][H] -> Wt [EG][H][D]
    transpose_convert<D, H><<<EG * (D / 64) * (H / 64), 256, 0, stream>>>(W1g, Wt);
    // h = relu(A @ W1 + b1) -> bf16
    moe_gemm<0, H, D><<<EG * 8 * (H / 128), 256, 0, stream>>>(
        Abf + (size_t)g * EG * CAP * D, Wt, b1 + (size_t)g * EG * H,
        Hbf, nullptr, nullptr, nullptr);
    // W2 [EG][H][O] -> Wt [EG][O][H]
    transpose_convert<H, O><<<EG * (H / 64) * (O / 64), 256, 0, stream>>>(W2g, Wt);
    // out[tok] += (h @ W2 + b2) * score
    moe_gemm<1, O, H><<<EG * 8 * (O / 128), 256, 0, stream>>>(
        Hbf, Wt, b2 + (size_t)g * EG * O,
        nullptr, out, scoresW + (size_t)g * EG * CAP, idxW + (size_t)g * EG * CAP);
  }
}

// Round 4
// 1062.414 us; speedup vs baseline: 1.2490x; 1.2490x over previous
//
#include <hip/hip_runtime.h>

typedef unsigned short u16;
typedef unsigned int   u32;
typedef unsigned long long u64;
typedef __attribute__((ext_vector_type(8))) short s16x8;
typedef __attribute__((ext_vector_type(4))) float f32x4;

// Problem dims
constexpr int B = 8192, D = 1024, H = 4096, O = 1024, E = 16, CAP = 1024;

__device__ __forceinline__ u16 f2bf(float f) {
  u32 u = __float_as_uint(f);
  u32 r = (u + 0x7FFFu + ((u >> 16) & 1u)) >> 16;   // RNE
  return (u16)r;
}

// ---------------------------------------------------------------- zero out + mask (probs is fully overwritten by softmax — skip it)
__global__ __launch_bounds__(256) void zero_kernel(float4* __restrict__ outp, int n4o,
                                                   float4* __restrict__ maskp, int n4m) {
  int i = blockIdx.x * blockDim.x + threadIdx.x;
  int stride = gridDim.x * blockDim.x;
  float4 z; z.x = z.y = z.z = z.w = 0.0f;
  for (int j = i; j < n4o; j += stride) outp[j] = z;
  for (int j = i; j < n4m; j += stride) maskp[j] = z;
}

// ---------------------------------------------------------------- router logits (x@Wr + br), float4 loads
__global__ __launch_bounds__(256) void router_kernel(const float* __restrict__ x,
    const float* __restrict__ Wr, const float* __restrict__ br,
    float* __restrict__ logits) {
  int t = blockIdx.x * 256 + threadIdx.x;     // [0, B*E)
  int b = t >> 4, e = t & 15;
  const float4* xr = (const float4*)(x + (size_t)b * D);
  float acc = 0.f;
#pragma unroll 4
  for (int k = 0; k < D / 4; k++) {
    float4 v = xr[k];
    const float* wc = Wr + (size_t)(k * 4) * E + e;
    acc = fmaf(v.x, wc[0], acc);
    acc = fmaf(v.y, wc[E], acc);
    acc = fmaf(v.z, wc[2 * E], acc);
    acc = fmaf(v.w, wc[3 * E], acc);
  }
  logits[t] = acc + br[e];
}

// ---------------------------------------------------------------- softmax over token axis (per expert column)
__global__ __launch_bounds__(1024) void softmax_colwise(const float* __restrict__ logits,
                                                        float* __restrict__ probs) {
  __shared__ float red[16];
  int e = blockIdx.x, t = threadIdx.x;
  float l[8];
  float mx = -1e30f;
#pragma unroll
  for (int i = 0; i < 8; i++) {
    l[i] = logits[(size_t)(t + i * 1024) * E + e];
    mx = fmaxf(mx, l[i]);
  }
#pragma unroll
  for (int o = 32; o > 0; o >>= 1) mx = fmaxf(mx, __shfl_xor(mx, o));
  if ((t & 63) == 0) red[t >> 6] = mx;
  __syncthreads();
  if (t < 64) {
    float v = (t < 16) ? red[t] : -1e30f;
#pragma unroll
    for (int o = 8; o > 0; o >>= 1) v = fmaxf(v, __shfl_xor(v, o));
    if (t == 0) red[0] = v;
  }
  __syncthreads();
  mx = red[0];
  __syncthreads();
  float s = 0.f;
#pragma unroll
  for (int i = 0; i < 8; i++) { l[i] = expf(l[i] - mx); s += l[i]; }
#pragma unroll
  for (int o = 32; o > 0; o >>= 1) s += __shfl_xor(s, o);
  if ((t & 63) == 0) red[t >> 6] = s;
  __syncthreads();
  if (t < 64) {
    float v = (t < 16) ? red[t] : 0.f;
#pragma unroll
    for (int o = 8; o > 0; o >>= 1) v += __shfl_xor(v, o);
    if (t == 0) red[0] = v;
  }
  __syncthreads();
  float inv = 1.0f / red[0];
#pragma unroll
  for (int i = 0; i < 8; i++)
    probs[(size_t)(t + i * 1024) * E + e] = l[i] * inv;
}

// ---------------------------------------------------------------- per-expert top-1024 via 8-pass radix select
// key = (valbits << 32) | ~idx  — all keys distinct, so exactly CAP keys >= threshold.
// Output order within an expert is arbitrary (doesn't affect output/probs/mask).
__global__ __launch_bounds__(1024) void topk_radix(const float* __restrict__ probs,
    float* __restrict__ scores, int* __restrict__ tidx, float* __restrict__ mask) {
  __shared__ u64 keys[8192];                  // 64 KB
  __shared__ u32 hist[256];
  __shared__ u64 pref_s;
  __shared__ u32 k_s;
  __shared__ u32 cnt_s;
  int e = blockIdx.x, t = threadIdx.x;
  for (int i = t; i < B; i += 1024) {
    float p = probs[(size_t)i * E + e];
    keys[i] = ((u64)__float_as_uint(p) << 32) | (u32)(0xFFFFFFFFu - (u32)i);
  }
  if (t == 0) cnt_s = 0;
  __syncthreads();
  u64 prefix = 0; u32 k = CAP;
  for (int shift = 56; shift >= 0; shift -= 8) {
    if (t < 256) hist[t] = 0;
    __syncthreads();
    u64 himask = (shift == 56) ? 0ull : (~0ull << (shift + 8));
    for (int i = t; i < B; i += 1024) {
      u64 kk = keys[i];
      if ((kk & himask) == (prefix & himask))
        atomicAdd(&hist[(u32)(kk >> shift) & 255u], 1u);
    }
    __syncthreads();
    if (t == 0) {
      u32 acc = 0; int bb = 255;
      for (; bb >= 0; bb--) {
        if (acc + hist[bb] >= k) break;
        acc += hist[bb];
      }
      if (bb < 0) bb = 0;                     // unreachable; safety
      pref_s = prefix | ((u64)(u32)bb << shift);
      k_s = k - acc;
    }
    __syncthreads();
    prefix = pref_s; k = k_s;
    __syncthreads();
  }
  // prefix == CAP-th largest key; select all keys >= prefix (exactly CAP of them)
  for (int i = t; i < B; i += 1024) {
    u64 kk = keys[i];
    if (kk >= prefix) {
      u32 slot = atomicAdd(&cnt_s, 1u);
      scores[e * CAP + slot] = __uint_as_float((u32)(kk >> 32));
      int b = (int)(0xFFFFFFFFu - (u32)kk);
      tidx[e * CAP + slot] = b;
      mask[(size_t)b * E + e] = 1.0f;
    }
  }
}

// ---------------------------------------------------------------- gather selected token rows -> bf16
__global__ __launch_bounds__(256) void gather_bf16(const float* __restrict__ x,
    const int* __restrict__ tidx, u16* __restrict__ Abf) {
  int blk = blockIdx.x;                        // e*CAP + c
  int row = tidx[blk];
  const float4* src = (const float4*)(x + (size_t)row * D);
  int t = threadIdx.x;
  float4 v = src[t];
  uint2 u;
  u.x = f2bf(v.x) | ((u32)f2bf(v.y) << 16);
  u.y = f2bf(v.z) | ((u32)f2bf(v.w) << 16);
  ((uint2*)(Abf + (size_t)blk * D))[t] = u;
}

// ---------------------------------------------------------------- transpose + f32->bf16: in [E][DR][DC] -> out [E][DC][DR]
template <int DR, int DC>
__global__ __launch_bounds__(256) void transpose_convert(const float* __restrict__ in,
                                                         u16* __restrict__ out) {
  __shared__ float tile[64][68];
  constexpr int TR = DR / 64, TC = DC / 64;
  int bid = blockIdx.x;
  int e = bid / (TR * TC);
  int rem = bid % (TR * TC);
  int tr = rem / TC, tc = rem % TC;
  int t = threadIdx.x;
  int r0 = t >> 4;            // 0..15
  int c0 = (t & 15) << 2;     // 0..60
  const float* src = in + (size_t)e * DR * DC + (size_t)(tr * 64) * DC + (size_t)tc * 64;
#pragma unroll
  for (int p = 0; p < 4; p++) {
    float4 v = *(const float4*)(src + (size_t)(p * 16 + r0) * DC + c0);
    tile[p * 16 + r0][c0 + 0] = v.x;
    tile[p * 16 + r0][c0 + 1] = v.y;
    tile[p * 16 + r0][c0 + 2] = v.z;
    tile[p * 16 + r0][c0 + 3] = v.w;
  }
  __syncthreads();
  u16* dst = out + (size_t)e * DR * DC + (size_t)(tc * 64) * DR + (size_t)tr * 64;
#pragma unroll
  for (int p = 0; p < 4; p++) {
    int hl = p * 16 + r0;
    uint2 u;
    u.x = f2bf(tile[c0 + 0][hl]) | ((u32)f2bf(tile[c0 + 1][hl]) << 16);
    u.y = f2bf(tile[c0 + 2][hl]) | ((u32)f2bf(tile[c0 + 3][hl]) << 16);
    *(uint2*)(dst + (size_t)hl * DR + c0) = u;
  }
}

// ---------------------------------------------------------------- batched bf16 GEMM, m97-style 128x128 tile, BK=64
// A: [E][1024][KTOT] bf16 row-major. Bt: [E][NTOT][KTOT] bf16 (B transposed).
// EPI 0: Hout = relu(A@B + bias) as bf16 [E][1024][NTOT]
// EPI 1: atomicAdd(out[tok], (A@B + bias) * score)
template <int EPI, int NTOT, int KTOT>
__global__ __launch_bounds__(256, 2) void moe_gemm(const u16* __restrict__ A,
    const u16* __restrict__ Bt, const float* __restrict__ bias,
    u16* __restrict__ Hout, float* __restrict__ outp,
    const float* __restrict__ scores, const int* __restrict__ tidx) {
  constexpr int NTM = 1024 / 128, NTN = NTOT / 128, NKT = KTOT / 64;
  constexpr int NWG = E * NTM * NTN;          // total workgroups (divisible by 8)
  __shared__ u16 Alds[128 * 64];
  __shared__ u16 Blds[128 * 64];
  // T1: XCD-aware swizzle — bijective since NWG % 8 == 0
  int bid = blockIdx.x;
  bid = (bid & 7) * (NWG / 8) + (bid >> 3);
  int e = bid / (NTM * NTN);
  int rem = bid % (NTM * NTN);
  int tm = rem / NTN, tn = rem % NTN;
  int tid = threadIdx.x, w = tid >> 6, lane = tid & 63;
  int wr = w >> 1, wc = w & 1;

  const u16* Abase = A + ((size_t)e * 1024 + tm * 128) * KTOT;
  const u16* Bbase = Bt + ((size_t)e * NTOT + tn * 128) * KTOT;
  int srow = lane >> 3;            // 0..7
  int scol = (lane & 7) * 8;       // bf16 elements (16B)

  f32x4 acc[4][4];
#pragma unroll
  for (int m = 0; m < 4; m++)
#pragma unroll
    for (int n = 0; n < 4; n++) { f32x4 z = {0.f, 0.f, 0.f, 0.f}; acc[m][n] = z; }

  for (int kt = 0; kt < NKT; kt++) {
    const u16* Ak = Abase + kt * 64;
    const u16* Bk = Bbase + kt * 64;
#pragma unroll
    for (int i = 0; i < 4; i++) {
      int grp = w * 4 + i;                 // 0..15
      int row = grp * 8 + srow;            // 0..127
      __builtin_amdgcn_global_load_lds(
          (const __attribute__((address_space(1))) void*)(Ak + (size_t)row * KTOT + scol),
          (__attribute__((address_space(3))) void*)(&Alds[grp * 512]), 16, 0, 0);
      __builtin_amdgcn_global_load_lds(
          (const __attribute__((address_space(1))) void*)(Bk + (size_t)row * KTOT + scol),
          (__attribute__((address_space(3))) void*)(&Blds[grp * 512]), 16, 0, 0);
    }
    __syncthreads();
#pragma unroll
    for (int kk = 0; kk < 2; kk++) {
      int kb = kk * 32 + (lane >> 4) * 8;
      s16x8 a[4], bfr[4];
#pragma unroll
      for (int m = 0; m < 4; m++)
        a[m] = *(const s16x8*)&Alds[(wr * 64 + m * 16 + (lane & 15)) * 64 + kb];
#pragma unroll
      for (int n = 0; n < 4; n++)
        bfr[n] = *(const s16x8*)&Blds[(wc * 64 + n * 16 + (lane & 15)) * 64 + kb];
#pragma unroll
      for (int m = 0; m < 4; m++)
#pragma unroll
        for (int n = 0; n < 4; n++)
          acc[m][n] = __builtin_amdgcn_mfma_f32_16x16x32_bf16(a[m], bfr[n], acc[m][n], 0, 0, 0);
    }
    __syncthreads();
  }

  int colb = tn * 128 + wc * 64 + (lane & 15);
  float bv[4];
#pragma unroll
  for (int n = 0; n < 4; n++) bv[n] = bias[(size_t)e * NTOT + colb + n * 16];

  if constexpr (EPI == 0) {
    u16* Hb = Hout + (size_t)e * 1024 * NTOT;
#pragma unroll
    for (int m = 0; m < 4; m++) {
#pragma unroll
      for (int j = 0; j < 4; j++) {
        int r = tm * 128 + wr * 64 + m * 16 + (lane >> 4) * 4 + j;
#pragma unroll
        for (int n = 0; n < 4; n++) {
          float v = acc[m][n][j] + bv[n];
          v = fmaxf(v, 0.0f);
          Hb[(size_t)r * NTOT + colb + n * 16] = f2bf(v);
        }
      }
    }
  } else {
#pragma unroll
    for (int m = 0; m < 4; m++) {
#pragma unroll
      for (int j = 0; j < 4; j++) {
        int rc = tm * 128 + wr * 64 + m * 16 + (lane >> 4) * 4 + j;
        float sc = scores[e * CAP + rc];
        int tok = tidx[e * CAP + rc];
        float* orow = outp + (size_t)tok * O;
#pragma unroll
        for (int n = 0; n < 4; n++) {
          float v = (acc[m][n][j] + bv[n]) * sc;
          atomicAdd(&orow[colb + n * 16], v);
        }
      }
    }
  }
}

// ----------------------------------------------------------------
extern "C" void kernel_launch(void* const* d_in, const int* in_sizes, int n_in,
                              void* d_out, int out_size, void* d_ws, size_t ws_size,
                              hipStream_t stream) {
  const float* x  = (const float*)d_in[0];
  const float* Wr = (const float*)d_in[1];
  const float* br = (const float*)d_in[2];
  const float* W1 = (const float*)d_in[3];
  const float* b1 = (const float*)d_in[4];
  const float* W2 = (const float*)d_in[5];
  const float* b2 = (const float*)d_in[6];

  float* out   = (float*)d_out;                 // [B][O]
  float* probs = out + (size_t)B * O;           // [B][E]
  float* mask  = probs + (size_t)B * E;         // [B][E]

  // workspace layout — full batch, all 16 experts (~417 MB; ws is 1 GB)
  char* ws = (char*)d_ws;
  float* logits  = (float*)ws;                              // 512 KB
  float* scoresW = (float*)(ws + (512u << 10));             // 64 KB
  int*   idxW    = (int*)(ws + (576u << 10));               // 64 KB
  u16* Abf = (u16*)(ws + (1u   << 20));                     // 32 MB   [E][CAP][D]
  u16* W1t = (u16*)(ws + (33u  << 20));                     // 128 MB  [E][H][D]
  u16* W2t = (u16*)(ws + (161u << 20));                     // 128 MB  [E][O][H]
  u16* Hbf = (u16*)(ws + (289u << 20));                     // 128 MB  [E][CAP][H]
  if (ws_size < (417u << 20)) return;                       // insufficient scratch -> visible failure

  zero_kernel<<<2048, 256, 0, stream>>>((float4*)out, (B * O) / 4,
                                        (float4*)mask, (B * E) / 4);
  router_kernel<<<(B * E) / 256, 256, 0, stream>>>(x, Wr, br, logits);
  softmax_colwise<<<E, 1024, 0, stream>>>(logits, probs);
  topk_radix<<<E, 1024, 0, stream>>>(probs, scoresW, idxW, mask);
  gather_bf16<<<E * CAP, 256, 0, stream>>>(x, idxW, Abf);

  // W1 [E][D][H] -> W1t [E][H][D]
  transpose_convert<D, H><<<E * (D / 64) * (H / 64), 256, 0, stream>>>(W1, W1t);
  // h = relu(A @ W1 + b1) -> bf16
  moe_gemm<0, H, D><<<E * 8 * (H / 128), 256, 0, stream>>>(
      Abf, W1t, b1, Hbf, nullptr, nullptr, nullptr);
  // W2 [E][H][O] -> W2t [E][O][H]
  transpose_convert<H, O><<<E * (H / 64) * (O / 64), 256, 0, stream>>>(W2, W2t);
  // out[tok] += (h @ W2 + b2) * score
  moe_gemm<1, O, H><<<E * 8 * (O / 128), 256, 0, stream>>>(
      Hbf, W2t, b2, nullptr, out, scoresW, idxW);
}